// Round 2
// baseline (599.907 us; speedup 1.0000x reference)
//
#include <hip/hip_runtime.h>
#include <hip/hip_bf16.h>

#define BB 32
#define TT 1600
#define EE 1024
#define AA 512
#define CC 10
#define KW 201

typedef __attribute__((ext_vector_type(8))) short short8;
typedef __attribute__((ext_vector_type(4))) float f32x4;

__device__ __forceinline__ float sigm(float x) { return 1.f / (1.f + expf(-x)); }

// pack 2 floats -> 2 bf16 (RNE): v_cvt_pk_bf16_f32
__device__ __forceinline__ unsigned int cvt2(float a, float b) {
    float2 f2; f2.x = a; f2.y = b;
    __hip_bfloat162 h = __float22bfloat162_rn(f2);
    unsigned int r;
    __builtin_memcpy(&r, &h, 4);
    return r;
}

// ---------------- ws layout (float units) ----------------
#define AF_OFF   0        // att_feat 32*10 = 320
#define R_OFF    320      // r = h_new + dec_proj: 16384
#define E_OFF    16704    // e scores: 51200
#define WBF_OFF  67904    // W_enc bf16: 524288 shorts = 262144 floats
// total ~330K floats = 1.29 MB

// ---------------- out layout (float units) ----------------
#define CTX_OFF 0
#define W_OFF   32768
#define H_OFF   83968
#define C_OFF   100352

// K1: blocks 0..319 = location conv (one block per (b,c), full T, no atomics);
//     blocks 320..831 = W_enc f32->bf16 conversion
__global__ void prep_kernel(const float* __restrict__ att_prev,
                            const float* __restrict__ conv_w,
                            const float* __restrict__ W_enc,
                            float* __restrict__ af,
                            unsigned short* __restrict__ Wbf) {
    int bx = blockIdx.x, tid = threadIdx.x;
    if (bx >= 320) {
        int i = (bx - 320) * 256 + tid;   // float4 unit, 131072 total
        float4 v = reinterpret_cast<const float4*>(W_enc)[i];
        uint2 p;
        p.x = cvt2(v.x, v.y);
        p.y = cvt2(v.z, v.w);
        reinterpret_cast<uint2*>(Wbf)[i] = p;
        return;
    }
    int b = bx / 10, c = bx % 10;
    __shared__ float xs[1808];     // t in [-100, 1707], padded
    __shared__ float wsm[KW];
    __shared__ float red[256];
    const float* xp = att_prev + b * TT;
    for (int i = tid; i < 1808; i += 256) {
        int g = i - 100;
        xs[i] = (g >= 0 && g < TT) ? xp[g] : 0.f;
    }
    if (tid < KW) wsm[tid] = conv_w[c * KW + tid];
    __syncthreads();
    float mx = 0.f;   // relu >= 0 so 0 is a valid identity
    #pragma unroll 1
    for (int sweep = 0; sweep < 2; ++sweep) {
        int t0 = sweep * 1024 + tid * 4;
        if (t0 >= TT) break;
        // rolling window: s_j = sum_k w[k]*xs[t0+j+k]
        float a0 = xs[t0], a1 = xs[t0 + 1], a2 = xs[t0 + 2], a3 = xs[t0 + 3];
        float s0 = 0.f, s1 = 0.f, s2 = 0.f, s3 = 0.f;
        #pragma unroll 4
        for (int k = 0; k < KW; ++k) {
            float w = wsm[k];
            s0 += w * a0; s1 += w * a1; s2 += w * a2; s3 += w * a3;
            a0 = a1; a1 = a2; a2 = a3;
            a3 = xs[t0 + k + 4];
        }
        mx = fmaxf(mx, fmaxf(fmaxf(s0, s1), fmaxf(s2, s3)));
    }
    red[tid] = mx; __syncthreads();
    for (int s = 128; s > 0; s >>= 1) {
        if (tid < s) red[tid] = fmaxf(red[tid], red[tid + s]);
        __syncthreads();
    }
    if (tid == 0) af[b * CC + c] = red[0];
}

// K2: gates + dec_proj + LSTM + r, one block per 2 a-values (grid 256, 512 thr).
__global__ void gates_lstm_kernel(const float* __restrict__ af,
                                  const float* __restrict__ att_h,
                                  const float* __restrict__ dec_z,
                                  const float* __restrict__ att_c,
                                  const float* __restrict__ W_ih,
                                  const float* __restrict__ W_hh,
                                  const float* __restrict__ W_dec,
                                  float* __restrict__ out,
                                  float* __restrict__ r_ws) {
    __shared__ float gsm[8][32];
    __shared__ float dsm[8][32];
    int tid = threadIdx.x;
    int a0 = blockIdx.x * 2;
    int b = tid & 31;
    if (tid < 256) {
        int u = tid >> 5;                 // 0..7 = gate*2 + ai
        int gate = u >> 1, ai = u & 1;
        int j = gate * 512 + a0 + ai;
        float s = 0.f;
        #pragma unroll
        for (int k = 0; k < 10; ++k) s += af[b * 10 + k] * W_ih[j * 10 + k];
        const float4* wr = reinterpret_cast<const float4*>(W_hh + (size_t)j * 512);
        const float4* hr = reinterpret_cast<const float4*>(att_h + b * 512);
        #pragma unroll 4
        for (int k = 0; k < 128; ++k) {
            float4 w = wr[k], h = hr[k];
            s += w.x * h.x + w.y * h.y + w.z * h.z + w.w * h.w;
        }
        gsm[u][b] = s;
    } else {
        int v = (tid - 256) >> 5;         // 0..7 = q*2 + ai
        int ai = v & 1, q = v >> 1;
        int a = a0 + ai;
        const float4* wr = reinterpret_cast<const float4*>(W_dec + (size_t)a * 1024) + q * 64;
        const float4* zr = reinterpret_cast<const float4*>(dec_z + (size_t)b * 1024) + q * 64;
        float s = 0.f;
        #pragma unroll 4
        for (int k = 0; k < 64; ++k) {
            float4 w = wr[k], z = zr[k];
            s += w.x * z.x + w.y * z.y + w.z * z.z + w.w * z.w;
        }
        dsm[v][b] = s;
    }
    __syncthreads();
    if (tid < 64) {
        int ai = tid >> 5;
        int a = a0 + ai;
        float ig = gsm[ai][b], fg = gsm[2 + ai][b], gg = gsm[4 + ai][b], og = gsm[6 + ai][b];
        float cn = sigm(fg) * att_c[b * 512 + a] + sigm(ig) * tanhf(gg);
        float hn = sigm(og) * tanhf(cn);
        out[H_OFF + b * 512 + a] = hn;
        out[C_OFF + b * 512 + a] = cn;
        float dec = dsm[ai][b] + dsm[2 + ai][b] + dsm[4 + ai][b] + dsm[6 + ai][b];
        r_ws[b * 512 + a] = hn + dec;
    }
}

// K3: fused score GEMM. Block = 128 M-rows x full N=512, K=1024, BK=32.
// 1024 thr = 16 waves (2m x 8n), wave tile 64x64.
// Pipelining (this round's change): B fragments are register-prefetched ONE
// chunk ahead (bc/bn double buffer, direct from L2 — Wbf is 1 MB, L2-hot), so
// the MFMAs of chunk c consume B(c) loaded during chunk c-1 and the L2 latency
// of B(c+1) hides under chunk c's 16 MFMAs. A stays in LDS (shared across the
// 8 wn-waves), dbuf, reg-prefetch depth 2. ONE raw barrier per chunk
// ("s_waitcnt lgkmcnt(0); s_barrier") — never drains vmcnt, so all global
// prefetches stay in flight across it.
__global__ void __launch_bounds__(1024, 4)
score_gemm_kernel(const float* __restrict__ enc,
                  const unsigned short* __restrict__ Wbf,
                  const float* __restrict__ b_enc,
                  const float* __restrict__ r_ws,
                  const float* __restrict__ W_g,
                  float* __restrict__ e_ws) {
    __shared__ __align__(16) short As[2][4096];   // 128 x 32 bf16, dbuf, k-major slots
    __shared__ float e_part[8][128];

    int tid = threadIdx.x;
    int lane = tid & 63, wv = tid >> 6;
    int wm = wv >> 3, wn = wv & 7;
    int col = lane & 15, quad = lane >> 4;
    int m0 = blockIdx.x * 128;

    // A staging: thread -> 4 floats; row=tid>>3, kq2=tid&7
    int arow = tid >> 3, akq2 = tid & 7;
    const float* asrc = enc + (size_t)(m0 + arow) * EE + akq2 * 4;
    int adst = (arow >> 4) * 512 + ((akq2 >> 1) * 16 + (arow & 15)) * 8 + (akq2 & 1) * 4;

    // B fragment pointers: lane reads Wbf[n][k0 + quad*8 .. +8), n = h*256+wn*32+nt*16+col
    const unsigned short* bp00 = Wbf + (size_t)(0 * 256 + wn * 32 + 0 * 16 + col) * EE + quad * 8;
    const unsigned short* bp01 = Wbf + (size_t)(0 * 256 + wn * 32 + 1 * 16 + col) * EE + quad * 8;
    const unsigned short* bp10 = Wbf + (size_t)(1 * 256 + wn * 32 + 0 * 16 + col) * EE + quad * 8;
    const unsigned short* bp11 = Wbf + (size_t)(1 * 256 + wn * 32 + 1 * 16 + col) * EE + quad * 8;

    f32x4 acc[4][2][2];
    #pragma unroll
    for (int mt = 0; mt < 4; ++mt)
        #pragma unroll
        for (int h = 0; h < 2; ++h)
            #pragma unroll
            for (int nt = 0; nt < 2; ++nt)
                acc[mt][h][nt] = (f32x4){0.f, 0.f, 0.f, 0.f};

    float4 av0, av1;
    short8 bc0, bc1, bc2, bc3;   // B frags for the chunk being computed
    short8 bn0, bn1, bn2, bn3;   // B frags being prefetched
    // prologue: B(0) -> bc; A(0) -> As[0]; issue A(1) into av1 (stays in flight)
    {
        bc0 = *reinterpret_cast<const short8*>(bp00);
        bc1 = *reinterpret_cast<const short8*>(bp01);
        bc2 = *reinterpret_cast<const short8*>(bp10);
        bc3 = *reinterpret_cast<const short8*>(bp11);
        float4 p = *reinterpret_cast<const float4*>(asrc);
        av1 = *reinterpret_cast<const float4*>(asrc + 32);
        uint2 q; q.x = cvt2(p.x, p.y); q.y = cvt2(p.z, p.w);
        *reinterpret_cast<uint2*>(&As[0][adst]) = q;
        asm volatile("s_waitcnt lgkmcnt(0)\n\ts_barrier" ::: "memory");
    }

// one K-chunk: compute with B-regs BC*, prefetch B(KC+1) into BN*, read A from
// As[RB], consume AVC (=A(KC+1)) into As[RB^1], issue AVI (=A(KC+2)).
#define SCORE_CHUNK(RB, AVC, AVI, BC0, BC1, BC2, BC3, BN0, BN1, BN2, BN3, KC, PREFB, PREFA, WR) \
    {                                                                                  \
        int k0 = (KC) * 32;                                                            \
        if (PREFB) {                                                                   \
            BN0 = *reinterpret_cast<const short8*>(bp00 + k0 + 32);                    \
            BN1 = *reinterpret_cast<const short8*>(bp01 + k0 + 32);                    \
            BN2 = *reinterpret_cast<const short8*>(bp10 + k0 + 32);                    \
            BN3 = *reinterpret_cast<const short8*>(bp11 + k0 + 32);                    \
        }                                                                              \
        if (PREFA)                                                                     \
            AVI = *reinterpret_cast<const float4*>(asrc + ((KC) + 2) * 32);            \
        short8 af0 = *reinterpret_cast<const short8*>(                                 \
            &As[RB][(wm * 4 + 0) * 512 + (quad * 16 + col) * 8]);                      \
        short8 af1 = *reinterpret_cast<const short8*>(                                 \
            &As[RB][(wm * 4 + 1) * 512 + (quad * 16 + col) * 8]);                      \
        short8 af2 = *reinterpret_cast<const short8*>(                                 \
            &As[RB][(wm * 4 + 2) * 512 + (quad * 16 + col) * 8]);                      \
        short8 af3 = *reinterpret_cast<const short8*>(                                 \
            &As[RB][(wm * 4 + 3) * 512 + (quad * 16 + col) * 8]);                      \
        __builtin_amdgcn_s_setprio(1);                                                 \
        acc[0][0][0] = __builtin_amdgcn_mfma_f32_16x16x32_bf16(af0, BC0, acc[0][0][0], 0, 0, 0); \
        acc[0][0][1] = __builtin_amdgcn_mfma_f32_16x16x32_bf16(af0, BC1, acc[0][0][1], 0, 0, 0); \
        acc[0][1][0] = __builtin_amdgcn_mfma_f32_16x16x32_bf16(af0, BC2, acc[0][1][0], 0, 0, 0); \
        acc[0][1][1] = __builtin_amdgcn_mfma_f32_16x16x32_bf16(af0, BC3, acc[0][1][1], 0, 0, 0); \
        acc[1][0][0] = __builtin_amdgcn_mfma_f32_16x16x32_bf16(af1, BC0, acc[1][0][0], 0, 0, 0); \
        acc[1][0][1] = __builtin_amdgcn_mfma_f32_16x16x32_bf16(af1, BC1, acc[1][0][1], 0, 0, 0); \
        acc[1][1][0] = __builtin_amdgcn_mfma_f32_16x16x32_bf16(af1, BC2, acc[1][1][0], 0, 0, 0); \
        acc[1][1][1] = __builtin_amdgcn_mfma_f32_16x16x32_bf16(af1, BC3, acc[1][1][1], 0, 0, 0); \
        acc[2][0][0] = __builtin_amdgcn_mfma_f32_16x16x32_bf16(af2, BC0, acc[2][0][0], 0, 0, 0); \
        acc[2][0][1] = __builtin_amdgcn_mfma_f32_16x16x32_bf16(af2, BC1, acc[2][0][1], 0, 0, 0); \
        acc[2][1][0] = __builtin_amdgcn_mfma_f32_16x16x32_bf16(af2, BC2, acc[2][1][0], 0, 0, 0); \
        acc[2][1][1] = __builtin_amdgcn_mfma_f32_16x16x32_bf16(af2, BC3, acc[2][1][1], 0, 0, 0); \
        acc[3][0][0] = __builtin_amdgcn_mfma_f32_16x16x32_bf16(af3, BC0, acc[3][0][0], 0, 0, 0); \
        acc[3][0][1] = __builtin_amdgcn_mfma_f32_16x16x32_bf16(af3, BC1, acc[3][0][1], 0, 0, 0); \
        acc[3][1][0] = __builtin_amdgcn_mfma_f32_16x16x32_bf16(af3, BC2, acc[3][1][0], 0, 0, 0); \
        acc[3][1][1] = __builtin_amdgcn_mfma_f32_16x16x32_bf16(af3, BC3, acc[3][1][1], 0, 0, 0); \
        __builtin_amdgcn_s_setprio(0);                                                 \
        if (WR) {                                                                      \
            uint2 q; q.x = cvt2(AVC.x, AVC.y); q.y = cvt2(AVC.z, AVC.w);               \
            *reinterpret_cast<uint2*>(&As[(RB) ^ 1][adst]) = q;                        \
        }                                                                              \
        asm volatile("s_waitcnt lgkmcnt(0)\n\ts_barrier" ::: "memory");                \
    }

    #pragma unroll 1
    for (int c = 0; c < 30; c += 2) {
        SCORE_CHUNK(0, av1, av0, bc0, bc1, bc2, bc3, bn0, bn1, bn2, bn3, c, 1, 1, 1)
        SCORE_CHUNK(1, av0, av1, bn0, bn1, bn2, bn3, bc0, bc1, bc2, bc3, c + 1, 1, 1, 1)
    }
    SCORE_CHUNK(0, av1, av0, bc0, bc1, bc2, bc3, bn0, bn1, bn2, bn3, 30, 1, 0, 1)
    SCORE_CHUNK(1, av0, av1, bn0, bn1, bn2, bn3, bc0, bc1, bc2, bc3, 31, 0, 0, 0)
#undef SCORE_CHUNK

    // epilogue: e_row_partial = sum_n wg[n]*tanh(acc + b_enc[n] + r[b][n])
    float wg[2][2], bn_[2][2];
    #pragma unroll
    for (int h = 0; h < 2; ++h)
        #pragma unroll
        for (int nt = 0; nt < 2; ++nt) {
            int n = h * 256 + wn * 32 + nt * 16 + col;
            wg[h][nt] = W_g[n];
            bn_[h][nt] = b_enc[n];
        }
    #pragma unroll
    for (int mt = 0; mt < 4; ++mt) {
        int mg = m0 + wm * 64 + mt * 16;   // 16-row groups never straddle batch rows
        int bb = mg / TT;
        float rr[2][2];
        #pragma unroll
        for (int h = 0; h < 2; ++h)
            #pragma unroll
            for (int nt = 0; nt < 2; ++nt)
                rr[h][nt] = r_ws[bb * AA + h * 256 + wn * 32 + nt * 16 + col];
        #pragma unroll
        for (int reg = 0; reg < 4; ++reg) {
            float p = 0.f;
            #pragma unroll
            for (int h = 0; h < 2; ++h)
                #pragma unroll
                for (int nt = 0; nt < 2; ++nt)
                    p += wg[h][nt] * tanhf(acc[mt][h][nt][reg] + bn_[h][nt] + rr[h][nt]);
            p += __shfl_xor(p, 1);
            p += __shfl_xor(p, 2);
            p += __shfl_xor(p, 4);
            p += __shfl_xor(p, 8);
            if (col == 0) e_part[wn][wm * 64 + mt * 16 + quad * 4 + reg] = p;
        }
    }
    __syncthreads();
    if (tid < 128) {
        float s = 0.f;
        #pragma unroll
        for (int i = 0; i < 8; ++i) s += e_part[i][tid];
        e_ws[m0 + tid] = s;
    }
}

// K4: softmax (recomputed per block, shift-invariant so b_g dropped) + ctx chunk.
__global__ void ctx_softmax_kernel(const float* __restrict__ enc,
                                   const float* __restrict__ e_ws,
                                   const int* __restrict__ lens,
                                   float* __restrict__ w_out,
                                   float* __restrict__ ctx) {
    int b = blockIdx.x, ch = blockIdx.y;
    int tid = threadIdx.x;
    __shared__ float w_sm[1600];
    __shared__ float red[512];
    __shared__ float part[8][128];
    int len = lens[b];
    const float* e = e_ws + b * TT;
    float mx = -3.4e38f;
    for (int t = tid; t < len; t += 512) mx = fmaxf(mx, e[t]);
    red[tid] = mx; __syncthreads();
    for (int s = 256; s > 0; s >>= 1) {
        if (tid < s) red[tid] = fmaxf(red[tid], red[tid + s]);
        __syncthreads();
    }
    mx = red[0]; __syncthreads();
    float sum = 0.f;
    for (int t = tid; t < TT; t += 512) {
        float p = (t < len) ? expf(2.f * (e[t] - mx)) : 0.f;
        w_sm[t] = p; sum += p;
    }
    red[tid] = sum; __syncthreads();
    for (int s = 256; s > 0; s >>= 1) {
        if (tid < s) red[tid] += red[tid + s];
        __syncthreads();
    }
    float inv = 1.f / red[0];
    __syncthreads();
    for (int t = tid; t < TT; t += 512) {
        float wv = w_sm[t] * inv;
        w_sm[t] = wv;
        if (ch == 0) w_out[b * TT + t] = wv;
    }
    __syncthreads();
    // ctx: wave w8 covers t in [w8*200, w8*200+200), lanes cover 128 cols as float2
    int lane2 = tid & 63, w8 = tid >> 6;
    int tb = w8 * 200;
    const float* base = enc + (size_t)(b * TT + tb) * EE + ch * 128 + lane2 * 2;
    float cx = 0.f, cy = 0.f;
    #pragma unroll 1
    for (int i = 0; i < 200; i += 8) {
        #pragma unroll
        for (int j = 0; j < 8; ++j) {
            float2 v = *reinterpret_cast<const float2*>(base + (size_t)(i + j) * EE);
            float ww = w_sm[tb + i + j];
            cx += ww * v.x; cy += ww * v.y;
        }
    }
    part[w8][lane2 * 2] = cx;
    part[w8][lane2 * 2 + 1] = cy;
    __syncthreads();
    if (tid < 128) {
        float s = 0.f;
        #pragma unroll
        for (int i = 0; i < 8; ++i) s += part[i][tid];
        ctx[b * EE + ch * 128 + tid] = s;
    }
}

extern "C" void kernel_launch(void* const* d_in, const int* in_sizes, int n_in,
                              void* d_out, int out_size, void* d_ws, size_t ws_size,
                              hipStream_t stream) {
    const float* enc      = (const float*)d_in[0];
    const int*   lens     = (const int*)d_in[1];
    const float* dec_z    = (const float*)d_in[2];
    const float* att_prev = (const float*)d_in[3];
    const float* att_h    = (const float*)d_in[4];
    const float* att_c    = (const float*)d_in[5];
    const float* W_enc    = (const float*)d_in[6];
    const float* b_enc    = (const float*)d_in[7];
    const float* W_dec    = (const float*)d_in[8];
    const float* conv_w   = (const float*)d_in[9];
    const float* W_ih     = (const float*)d_in[10];
    const float* W_hh     = (const float*)d_in[11];
    const float* W_g      = (const float*)d_in[12];

    float* out = (float*)d_out;
    float* ws  = (float*)d_ws;
    float* af   = ws + AF_OFF;
    float* r_ws = ws + R_OFF;
    float* e_ws = ws + E_OFF;
    unsigned short* Wbf = (unsigned short*)(ws + WBF_OFF);

    prep_kernel<<<832, 256, 0, stream>>>(att_prev, conv_w, W_enc, af, Wbf);
    gates_lstm_kernel<<<256, 512, 0, stream>>>(af, att_h, dec_z, att_c,
                                               W_ih, W_hh, W_dec, out, r_ws);
    score_gemm_kernel<<<400, 1024, 0, stream>>>(enc, Wbf, b_enc, r_ws, W_g, e_ws);
    ctx_softmax_kernel<<<dim3(BB, 8), 512, 0, stream>>>(enc, e_ws, lens,
                                                        out + W_OFF, out + CTX_OFF);
}

// Round 4
// 481.625 us; speedup vs baseline: 1.2456x; 1.2456x over previous
//
#include <hip/hip_runtime.h>
#include <hip/hip_bf16.h>

#define BB 32
#define TT 1600
#define EE 1024
#define AA 512
#define CC 10
#define KW 201

typedef __attribute__((ext_vector_type(8))) short short8;
typedef __attribute__((ext_vector_type(4))) float f32x4;

__device__ __forceinline__ float sigm(float x) { return 1.f / (1.f + expf(-x)); }

// pack 2 floats -> 2 bf16 (RNE): v_cvt_pk_bf16_f32
__device__ __forceinline__ unsigned int cvt2(float a, float b) {
    float2 f2; f2.x = a; f2.y = b;
    __hip_bfloat162 h = __float22bfloat162_rn(f2);
    unsigned int r;
    __builtin_memcpy(&r, &h, 4);
    return r;
}

// async global->LDS 16 B/lane (global_load_lds_dwordx4); dest must be lane-linear
__device__ __forceinline__ void gl_lds16(const void* g, void* l) {
    __builtin_amdgcn_global_load_lds(
        (const __attribute__((address_space(1))) unsigned int*)g,
        (__attribute__((address_space(3))) unsigned int*)l, 16, 0, 0);
}

// ---------------- ws layout (float units) ----------------
#define AF_OFF   0        // att_feat 32*10 = 320
#define R_OFF    320      // r = h_new + dec_proj: 16384
#define E_OFF    16704    // e scores: 51200
#define WBF_OFF  67904    // W_enc bf16: 524288 shorts = 262144 floats
// total ~330K floats = 1.29 MB

// ---------------- out layout (float units) ----------------
#define CTX_OFF 0
#define W_OFF   32768
#define H_OFF   83968
#define C_OFF   100352

// K1: blocks 0..319 = location conv (one block per (b,c), full T, no atomics);
//     blocks 320..831 = W_enc f32->bf16 conversion
__global__ void prep_kernel(const float* __restrict__ att_prev,
                            const float* __restrict__ conv_w,
                            const float* __restrict__ W_enc,
                            float* __restrict__ af,
                            unsigned short* __restrict__ Wbf) {
    int bx = blockIdx.x, tid = threadIdx.x;
    if (bx >= 320) {
        int i = (bx - 320) * 256 + tid;   // float4 unit, 131072 total
        float4 v = reinterpret_cast<const float4*>(W_enc)[i];
        uint2 p;
        p.x = cvt2(v.x, v.y);
        p.y = cvt2(v.z, v.w);
        reinterpret_cast<uint2*>(Wbf)[i] = p;
        return;
    }
    int b = bx / 10, c = bx % 10;
    __shared__ float xs[1808];     // t in [-100, 1707], padded
    __shared__ float wsm[KW];
    __shared__ float red[256];
    const float* xp = att_prev + b * TT;
    for (int i = tid; i < 1808; i += 256) {
        int g = i - 100;
        xs[i] = (g >= 0 && g < TT) ? xp[g] : 0.f;
    }
    if (tid < KW) wsm[tid] = conv_w[c * KW + tid];
    __syncthreads();
    float mx = 0.f;   // relu >= 0 so 0 is a valid identity
    #pragma unroll 1
    for (int sweep = 0; sweep < 2; ++sweep) {
        int t0 = sweep * 1024 + tid * 4;
        if (t0 >= TT) break;
        // rolling window: s_j = sum_k w[k]*xs[t0+j+k]
        float a0 = xs[t0], a1 = xs[t0 + 1], a2 = xs[t0 + 2], a3 = xs[t0 + 3];
        float s0 = 0.f, s1 = 0.f, s2 = 0.f, s3 = 0.f;
        #pragma unroll 4
        for (int k = 0; k < KW; ++k) {
            float w = wsm[k];
            s0 += w * a0; s1 += w * a1; s2 += w * a2; s3 += w * a3;
            a0 = a1; a1 = a2; a2 = a3;
            a3 = xs[t0 + k + 4];
        }
        mx = fmaxf(mx, fmaxf(fmaxf(s0, s1), fmaxf(s2, s3)));
    }
    red[tid] = mx; __syncthreads();
    for (int s = 128; s > 0; s >>= 1) {
        if (tid < s) red[tid] = fmaxf(red[tid], red[tid + s]);
        __syncthreads();
    }
    if (tid == 0) af[b * CC + c] = red[0];
}

// K2: gates + dec_proj + LSTM + r, one block per 2 a-values (grid 256, 512 thr).
__global__ void gates_lstm_kernel(const float* __restrict__ af,
                                  const float* __restrict__ att_h,
                                  const float* __restrict__ dec_z,
                                  const float* __restrict__ att_c,
                                  const float* __restrict__ W_ih,
                                  const float* __restrict__ W_hh,
                                  const float* __restrict__ W_dec,
                                  float* __restrict__ out,
                                  float* __restrict__ r_ws) {
    __shared__ float gsm[8][32];
    __shared__ float dsm[8][32];
    int tid = threadIdx.x;
    int a0 = blockIdx.x * 2;
    int b = tid & 31;
    if (tid < 256) {
        int u = tid >> 5;                 // 0..7 = gate*2 + ai
        int gate = u >> 1, ai = u & 1;
        int j = gate * 512 + a0 + ai;
        float s = 0.f;
        #pragma unroll
        for (int k = 0; k < 10; ++k) s += af[b * 10 + k] * W_ih[j * 10 + k];
        const float4* wr = reinterpret_cast<const float4*>(W_hh + (size_t)j * 512);
        const float4* hr = reinterpret_cast<const float4*>(att_h + b * 512);
        #pragma unroll 4
        for (int k = 0; k < 128; ++k) {
            float4 w = wr[k], h = hr[k];
            s += w.x * h.x + w.y * h.y + w.z * h.z + w.w * h.w;
        }
        gsm[u][b] = s;
    } else {
        int v = (tid - 256) >> 5;         // 0..7 = q*2 + ai
        int ai = v & 1, q = v >> 1;
        int a = a0 + ai;
        const float4* wr = reinterpret_cast<const float4*>(W_dec + (size_t)a * 1024) + q * 64;
        const float4* zr = reinterpret_cast<const float4*>(dec_z + (size_t)b * 1024) + q * 64;
        float s = 0.f;
        #pragma unroll 4
        for (int k = 0; k < 64; ++k) {
            float4 w = wr[k], z = zr[k];
            s += w.x * z.x + w.y * z.y + w.z * z.z + w.w * z.w;
        }
        dsm[v][b] = s;
    }
    __syncthreads();
    if (tid < 64) {
        int ai = tid >> 5;
        int a = a0 + ai;
        float ig = gsm[ai][b], fg = gsm[2 + ai][b], gg = gsm[4 + ai][b], og = gsm[6 + ai][b];
        float cn = sigm(fg) * att_c[b * 512 + a] + sigm(ig) * tanhf(gg);
        float hn = sigm(og) * tanhf(cn);
        out[H_OFF + b * 512 + a] = hn;
        out[C_OFF + b * 512 + a] = cn;
        float dec = dsm[ai][b] + dsm[2 + ai][b] + dsm[4 + ai][b] + dsm[6 + ai][b];
        r_ws[b * 512 + a] = hn + dec;
    }
}

// K3: fused score GEMM, counted-vmcnt pipeline (T3+T4).
// Block = 128 M x 512 N, K=1024, BK=32. 1024 thr = 16 waves (2m x 8n), wave 64x64.
// ALL staging via global_load_lds (zero staging registers -> no spill, the R2 bug).
// A staged as f32 (cvt->bf16 in-reg, 16 cvt_pk/chunk hides under MFMA); A cells
// XOR-swizzled (sigma(L)=L^((L>>3)&7), involution) via pre-swizzled GLOBAL src +
// swizzled read offsets (rule: both-sides-or-neither); LDS stays lane-linear.
// B keeps the R0 slot layout (2-way bank = free). Triple-buffered A and B:
// chunk c computes buf c%3 while c+1 is landing and c+2 is being issued.
// Exactly 3 gl_lds per thread per chunk (A,B,B) => end-of-chunk
// "s_waitcnt vmcnt(3); s_barrier" retires chunk c+1's stage, keeps c+2 in flight.
// vmcnt is NEVER drained to 0 in the main loop.
__global__ void __launch_bounds__(1024, 4)
score_gemm_kernel(const float* __restrict__ enc,
                  const unsigned short* __restrict__ Wbf,
                  const float* __restrict__ b_enc,
                  const float* __restrict__ r_ws,
                  const float* __restrict__ W_g,
                  float* __restrict__ e_ws) {
    __shared__ __align__(16) short Bs[3][16384];   // 3 x (512n x 32k) bf16 slots, 96 KB
    __shared__ __align__(16) char  AsB[3][16384];  // 3 x (128m x 32k) f32 swizzled, 48 KB
    __shared__ float e_part[8][128];               // 4 KB  (total 148 KB LDS)

    int tid = threadIdx.x;
    int lane = tid & 63, wv = tid >> 6;
    int wm = wv >> 3, wn = wv & 7;
    int col = lane & 15, quad = lane >> 4;
    int m0 = blockIdx.x * 128;

    // ---- A staging src (per-lane, pre-swizzled): thread covers physical cell
    // P = tid&127 in m-group tid>>7; logical cell L = P ^ ((P>>3)&7) (involution);
    // L = s*2+sub, s = koct*16+row: holds A[row][koct*8+sub*4 .. +4]
    int agrp = tid >> 7;
    int P = tid & 127;
    int Lc = P ^ ((P >> 3) & 7);
    int as_ = Lc >> 1, asub = Lc & 1;
    int akoct = as_ >> 4, arowin = as_ & 15;
    const float* asrc = enc + (size_t)(m0 + agrp * 16 + arowin) * EE + akoct * 8 + asub * 4;
    // A dst: lane-linear byte tid*16 (= agrp*2048 + P*16)

    // ---- A read offsets (within one 2 KB m-group): logical cells for lane frag
    int L0 = (quad * 16 + col) * 2;
    int L1 = L0 + 1;
    int p0 = (L0 ^ ((L0 >> 3) & 7)) * 16;   // physical byte offsets
    int p1 = (L1 ^ ((L1 >> 3) & 7)) * 16;

    // ---- B staging src: issue j covers n-group (tid>>6)+j*16, slot tid&63
    int bslot = tid & 63;
    int boct = bslot >> 4, brow = bslot & 15;
    const unsigned short* bsrc0 = Wbf + (size_t)((tid >> 6) * 16 + brow) * EE + boct * 8;
    const unsigned short* bsrc1 = Wbf + (size_t)(((tid >> 6) + 16) * 16 + brow) * EE + boct * 8;

    f32x4 acc[4][2][2];
    #pragma unroll
    for (int mt = 0; mt < 4; ++mt)
        #pragma unroll
        for (int h = 0; h < 2; ++h)
            #pragma unroll
            for (int nt = 0; nt < 2; ++nt)
                acc[mt][h][nt] = (f32x4){0.f, 0.f, 0.f, 0.f};

    // prologue: stage chunks 0 and 1 (6 issues); wait oldest 3 (chunk 0), keep
    // chunk 1 in flight.
    gl_lds16(asrc,              &AsB[0][tid * 16]);
    gl_lds16(bsrc0,             &Bs[0][tid * 8]);
    gl_lds16(bsrc1,             &Bs[0][8192 + tid * 8]);
    gl_lds16(asrc + 32,         &AsB[1][tid * 16]);
    gl_lds16(bsrc0 + 32,        &Bs[1][tid * 8]);
    gl_lds16(bsrc1 + 32,        &Bs[1][8192 + tid * 8]);
    asm volatile("s_waitcnt vmcnt(3)" ::: "memory");
    __builtin_amdgcn_s_barrier();

// one chunk: stage (KC+2) into buf SB, compute buf RB, then vmcnt(WN)+barrier
#define SCORE_CHUNK(KC, RB, SB, STAGE, SYNC, WN)                                \
    {                                                                           \
        if (STAGE) {                                                            \
            gl_lds16(asrc + ((KC) + 2) * 32,  &AsB[SB][tid * 16]);              \
            gl_lds16(bsrc0 + ((KC) + 2) * 32, &Bs[SB][tid * 8]);                \
            gl_lds16(bsrc1 + ((KC) + 2) * 32, &Bs[SB][8192 + tid * 8]);         \
        }                                                                       \
        short8 af[4];                                                           \
        _Pragma("unroll")                                                       \
        for (int mt = 0; mt < 4; ++mt) {                                        \
            const char* ab = &AsB[RB][(wm * 4 + mt) * 2048];                    \
            float4 x = *reinterpret_cast<const float4*>(ab + p0);               \
            float4 y = *reinterpret_cast<const float4*>(ab + p1);               \
            union { short8 s; unsigned int u[4]; } cv;                          \
            cv.u[0] = cvt2(x.x, x.y); cv.u[1] = cvt2(x.z, x.w);                 \
            cv.u[2] = cvt2(y.x, y.y); cv.u[3] = cvt2(y.z, y.w);                 \
            af[mt] = cv.s;                                                      \
        }                                                                       \
        short8 bf[2][2];                                                        \
        _Pragma("unroll")                                                       \
        for (int h = 0; h < 2; ++h)                                             \
            _Pragma("unroll")                                                   \
            for (int nt = 0; nt < 2; ++nt)                                      \
                bf[h][nt] = *reinterpret_cast<const short8*>(                   \
                    &Bs[RB][(h * 16 + wn * 2 + nt) * 512 + (quad * 16 + col) * 8]); \
        __builtin_amdgcn_s_setprio(1);                                          \
        _Pragma("unroll")                                                       \
        for (int mt = 0; mt < 4; ++mt)                                          \
            _Pragma("unroll")                                                   \
            for (int h = 0; h < 2; ++h)                                         \
                _Pragma("unroll")                                               \
                for (int nt = 0; nt < 2; ++nt)                                  \
                    acc[mt][h][nt] = __builtin_amdgcn_mfma_f32_16x16x32_bf16(   \
                        af[mt], bf[h][nt], acc[mt][h][nt], 0, 0, 0);            \
        __builtin_amdgcn_s_setprio(0);                                          \
        if (SYNC) {                                                             \
            asm volatile("s_waitcnt vmcnt(" #WN ")" ::: "memory");              \
            __builtin_amdgcn_s_barrier();                                       \
        }                                                                       \
    }

    #pragma unroll 1
    for (int c = 0; c < 30; c += 3) {
        SCORE_CHUNK(c,     0, 2, 1, 1, 3)
        SCORE_CHUNK(c + 1, 1, 0, 1, 1, 3)
        SCORE_CHUNK(c + 2, 2, 1, 1, 1, 3)
    }
    SCORE_CHUNK(30, 0, 0, 0, 1, 0)   // drain last stage (chunk 31), barrier
    SCORE_CHUNK(31, 1, 0, 0, 0, 0)   // compute only
#undef SCORE_CHUNK

    // epilogue: e_row_partial = sum_n wg[n]*tanh(acc + b_enc[n] + r[b][n])
    float wg[2][2], bn_[2][2];
    #pragma unroll
    for (int h = 0; h < 2; ++h)
        #pragma unroll
        for (int nt = 0; nt < 2; ++nt) {
            int n = h * 256 + wn * 32 + nt * 16 + col;
            wg[h][nt] = W_g[n];
            bn_[h][nt] = b_enc[n];
        }
    #pragma unroll
    for (int mt = 0; mt < 4; ++mt) {
        int mg = m0 + wm * 64 + mt * 16;   // 16-row groups never straddle batch rows
        int bb = mg / TT;
        float rr[2][2];
        #pragma unroll
        for (int h = 0; h < 2; ++h)
            #pragma unroll
            for (int nt = 0; nt < 2; ++nt)
                rr[h][nt] = r_ws[bb * AA + h * 256 + wn * 32 + nt * 16 + col];
        #pragma unroll
        for (int reg = 0; reg < 4; ++reg) {
            float p = 0.f;
            #pragma unroll
            for (int h = 0; h < 2; ++h)
                #pragma unroll
                for (int nt = 0; nt < 2; ++nt)
                    p += wg[h][nt] * tanhf(acc[mt][h][nt][reg] + bn_[h][nt] + rr[h][nt]);
            p += __shfl_xor(p, 1);
            p += __shfl_xor(p, 2);
            p += __shfl_xor(p, 4);
            p += __shfl_xor(p, 8);
            if (col == 0) e_part[wn][wm * 64 + mt * 16 + quad * 4 + reg] = p;
        }
    }
    __syncthreads();
    if (tid < 128) {
        float s = 0.f;
        #pragma unroll
        for (int i = 0; i < 8; ++i) s += e_part[i][tid];
        e_ws[m0 + tid] = s;
    }
}

// K4: softmax (recomputed per block, shift-invariant so b_g dropped) + ctx chunk.
__global__ void ctx_softmax_kernel(const float* __restrict__ enc,
                                   const float* __restrict__ e_ws,
                                   const int* __restrict__ lens,
                                   float* __restrict__ w_out,
                                   float* __restrict__ ctx) {
    int b = blockIdx.x, ch = blockIdx.y;
    int tid = threadIdx.x;
    __shared__ float w_sm[1600];
    __shared__ float red[512];
    __shared__ float part[8][128];
    int len = lens[b];
    const float* e = e_ws + b * TT;
    float mx = -3.4e38f;
    for (int t = tid; t < len; t += 512) mx = fmaxf(mx, e[t]);
    red[tid] = mx; __syncthreads();
    for (int s = 256; s > 0; s >>= 1) {
        if (tid < s) red[tid] = fmaxf(red[tid], red[tid + s]);
        __syncthreads();
    }
    mx = red[0]; __syncthreads();
    float sum = 0.f;
    for (int t = tid; t < TT; t += 512) {
        float p = (t < len) ? expf(2.f * (e[t] - mx)) : 0.f;
        w_sm[t] = p; sum += p;
    }
    red[tid] = sum; __syncthreads();
    for (int s = 256; s > 0; s >>= 1) {
        if (tid < s) red[tid] += red[tid + s];
        __syncthreads();
    }
    float inv = 1.f / red[0];
    __syncthreads();
    for (int t = tid; t < TT; t += 512) {
        float wv = w_sm[t] * inv;
        w_sm[t] = wv;
        if (ch == 0) w_out[b * TT + t] = wv;
    }
    __syncthreads();
    // ctx: wave w8 covers t in [w8*200, w8*200+200), lanes cover 128 cols as float2
    int lane2 = tid & 63, w8 = tid >> 6;
    int tb = w8 * 200;
    const float* base = enc + (size_t)(b * TT + tb) * EE + ch * 128 + lane2 * 2;
    float cx = 0.f, cy = 0.f;
    #pragma unroll 1
    for (int i = 0; i < 200; i += 8) {
        #pragma unroll
        for (int j = 0; j < 8; ++j) {
            float2 v = *reinterpret_cast<const float2*>(base + (size_t)(i + j) * EE);
            float ww = w_sm[tb + i + j];
            cx += ww * v.x; cy += ww * v.y;
        }
    }
    part[w8][lane2 * 2] = cx;
    part[w8][lane2 * 2 + 1] = cy;
    __syncthreads();
    if (tid < 128) {
        float s = 0.f;
        #pragma unroll
        for (int i = 0; i < 8; ++i) s += part[i][tid];
        ctx[b * EE + ch * 128 + tid] = s;
    }
}

extern "C" void kernel_launch(void* const* d_in, const int* in_sizes, int n_in,
                              void* d_out, int out_size, void* d_ws, size_t ws_size,
                              hipStream_t stream) {
    const float* enc      = (const float*)d_in[0];
    const int*   lens     = (const int*)d_in[1];
    const float* dec_z    = (const float*)d_in[2];
    const float* att_prev = (const float*)d_in[3];
    const float* att_h    = (const float*)d_in[4];
    const float* att_c    = (const float*)d_in[5];
    const float* W_enc    = (const float*)d_in[6];
    const float* b_enc    = (const float*)d_in[7];
    const float* W_dec    = (const float*)d_in[8];
    const float* conv_w   = (const float*)d_in[9];
    const float* W_ih     = (const float*)d_in[10];
    const float* W_hh     = (const float*)d_in[11];
    const float* W_g      = (const float*)d_in[12];

    float* out = (float*)d_out;
    float* ws  = (float*)d_ws;
    float* af   = ws + AF_OFF;
    float* r_ws = ws + R_OFF;
    float* e_ws = ws + E_OFF;
    unsigned short* Wbf = (unsigned short*)(ws + WBF_OFF);

    prep_kernel<<<832, 256, 0, stream>>>(att_prev, conv_w, W_enc, af, Wbf);
    gates_lstm_kernel<<<256, 512, 0, stream>>>(af, att_h, dec_z, att_c,
                                               W_ih, W_hh, W_dec, out, r_ws);
    score_gemm_kernel<<<400, 1024, 0, stream>>>(enc, Wbf, b_enc, r_ws, W_g, e_ws);
    ctx_softmax_kernel<<<dim3(BB, 8), 512, 0, stream>>>(enc, e_ws, lens,
                                                        out + W_OFF, out + CTX_OFF);
}